// Round 1
// baseline (549.570 us; speedup 1.0000x reference)
//
#include <hip/hip_runtime.h>

// Divergence of a periodic 3-component field on a 256^3 grid, batch 2.
// x shape: (2, 3, 256, 256, 256) fp32, out shape: (2, 256, 256, 256) fp32.
// out[b,z,y,x] = 0.5 * ( (u[z,y,x+1]-u[z,y,x-1])            // axis -1, periodic
//                      + (v[z,y+1,x]-v[z,y-1,x])            // axis -2, periodic
//                      + (w[z+1,y+1,x]-w[z-1,y-1,x]) )      // axes -3,-2, periodic

#define N     256
#define PLANE (N * N)        // 65536
#define VOL   (N * N * N)    // 16777216

__global__ __launch_bounds__(256)
void calc_divergence_4406636445920_kernel(const float* __restrict__ x,
                                          float* __restrict__ out) {
    const int tx = threadIdx.x;                       // 0..63, 4 x-elems each
    const int x0 = tx << 2;                           // 0,4,...,252
    const int y  = blockIdx.y * blockDim.y + threadIdx.y;  // 0..255
    const int bz = blockIdx.z;                        // 0..511  (b*256 + z)
    const int z  = bz & (N - 1);
    const int b  = bz >> 8;

    const float* __restrict__ u = x + (size_t)(b * 3 + 0) * VOL;
    const float* __restrict__ v = x + (size_t)(b * 3 + 1) * VOL;
    const float* __restrict__ w = x + (size_t)(b * 3 + 2) * VOL;

    const int ym = (y == 0)     ? N - 1 : y - 1;
    const int yp = (y == N - 1) ? 0     : y + 1;
    const int zm = (z == 0)     ? N - 1 : z - 1;
    const int zp = (z == N - 1) ? 0     : z + 1;

    const int rowz = z * PLANE;
    const int rowc = rowz + y * N;

    // u: center vector + two wrap-around edge scalars for the x-shift
    const float4 uc = *(const float4*)(u + rowc + x0);
    const float  ul = u[rowc + ((x0 == 0)     ? N - 1 : x0 - 1)];
    const float  ur = u[rowc + ((x0 == N - 4) ? 0     : x0 + 4)];

    // v: y+1 / y-1 rows, same z-plane
    const float4 vp = *(const float4*)(v + rowz + yp * N + x0);
    const float4 vm = *(const float4*)(v + rowz + ym * N + x0);

    // w: (z+1, y+1) and (z-1, y-1)
    const float4 wp = *(const float4*)(w + zp * PLANE + yp * N + x0);
    const float4 wm = *(const float4*)(w + zm * PLANE + ym * N + x0);

    float4 o;
    o.x = 0.5f * ((uc.y - ul)   + (vp.x - vm.x) + (wp.x - wm.x));
    o.y = 0.5f * ((uc.z - uc.x) + (vp.y - vm.y) + (wp.y - wm.y));
    o.z = 0.5f * ((uc.w - uc.y) + (vp.z - vm.z) + (wp.z - wm.z));
    o.w = 0.5f * ((ur   - uc.z) + (vp.w - vm.w) + (wp.w - wm.w));

    *(float4*)(out + (size_t)b * VOL + rowc + x0) = o;
}

extern "C" void kernel_launch(void* const* d_in, const int* in_sizes, int n_in,
                              void* d_out, int out_size, void* d_ws, size_t ws_size,
                              hipStream_t stream) {
    const float* xin = (const float*)d_in[0];
    float* out = (float*)d_out;

    dim3 block(64, 4, 1);        // 64 threads * 4 floats = one full x-row; 4 y-rows/block
    dim3 grid(1, N / 4, 2 * N);  // grid.z = b*256 + z

    calc_divergence_4406636445920_kernel<<<grid, block, 0, stream>>>(xin, out);
}

// Round 2
// 548.051 us; speedup vs baseline: 1.0028x; 1.0028x over previous
//
#include <hip/hip_runtime.h>

// Divergence of a periodic 3-component field on a 256^3 grid, batch 2.
// out[b,z,y,x] = 0.5 * ( (u[z,y,x+1]-u[z,y,x-1])
//                      + (v[z,y+1,x]-v[z,y-1,x])
//                      + (w[z+1,y+1,x]-w[z-1,y-1,x]) ), all periodic.
//
// Layout decisions (R1):
//  - 1D grid with XCD swizzle: lin%8 picks a 64-plane z-chunk so each XCD's
//    L2 streams contiguous z; the w z+1 halo plane is re-read 2 z-steps
//    later from the same L2 (~1 MB reuse distance << 4 MB).
//  - One wave == one periodic x-row (64 lanes x float4) -> x-wrap neighbors
//    come from __shfl with mod-64 lane wrap, no edge loads.
//  - u is read exactly once, out written once -> non-temporal, keep L2/L3
//    capacity for the reused v/w halo rows/planes.

#define N     256
#define PLANE (N * N)
#define VOL   (N * N * N)

typedef float f4 __attribute__((ext_vector_type(4)));

__global__ __launch_bounds__(256)
void calc_divergence_4406636445920_kernel(const float* __restrict__ x,
                                          float* __restrict__ out) {
    const int tx = threadIdx.x;            // lane in wave == x-position
    const int x0 = tx << 2;

    // XCD-aware swizzle: lin%8 -> z-chunk, then y-blocks fastest within a z.
    const int lin   = blockIdx.x;          // 0..32767
    const int chunk = lin & 7;             // -> XCD (heuristic)
    const int s     = lin >> 3;            // 0..4095 within chunk
    const int yblk  = s & 63;              // 64 y-blocks of 4 rows
    const int bz    = chunk * 64 + (s >> 6);   // 0..511
    const int z     = bz & (N - 1);
    const int b     = bz >> 8;
    const int y     = (yblk << 2) + threadIdx.y;

    const float* __restrict__ u = x + (size_t)(b * 3 + 0) * VOL;
    const float* __restrict__ v = x + (size_t)(b * 3 + 1) * VOL;
    const float* __restrict__ w = x + (size_t)(b * 3 + 2) * VOL;

    const int ym = (y == 0)     ? N - 1 : y - 1;
    const int yp = (y == N - 1) ? 0     : y + 1;
    const int zm = (z == 0)     ? N - 1 : z - 1;
    const int zp = (z == N - 1) ? 0     : z + 1;

    const int rowz = z * PLANE;
    const int rowc = rowz + y * N;

    // u: one NT vector load; x+-1 via lane shuffle (wave wrap == periodic wrap)
    const f4 uc = __builtin_nontemporal_load((const f4*)(u + rowc + x0));
    const float ul = __shfl(uc.w, (tx + 63) & 63);   // u[x0-1] (periodic)
    const float ur = __shfl(uc.x, (tx + 1)  & 63);   // u[x0+4] (periodic)

    const f4 vp = *(const f4*)(v + rowz + yp * N + x0);
    const f4 vm = *(const f4*)(v + rowz + ym * N + x0);
    const f4 wp = *(const f4*)(w + zp * PLANE + yp * N + x0);
    const f4 wm = *(const f4*)(w + zm * PLANE + ym * N + x0);

    f4 o;
    o.x = 0.5f * ((uc.y - ul)   + (vp.x - vm.x) + (wp.x - wm.x));
    o.y = 0.5f * ((uc.z - uc.x) + (vp.y - vm.y) + (wp.y - wm.y));
    o.z = 0.5f * ((uc.w - uc.y) + (vp.z - vm.z) + (wp.z - wm.z));
    o.w = 0.5f * ((ur   - uc.z) + (vp.w - vm.w) + (wp.w - wm.w));

    __builtin_nontemporal_store(o, (f4*)(out + (size_t)b * VOL + rowc + x0));
}

extern "C" void kernel_launch(void* const* d_in, const int* in_sizes, int n_in,
                              void* d_out, int out_size, void* d_ws, size_t ws_size,
                              hipStream_t stream) {
    const float* xin = (const float*)d_in[0];
    float* out = (float*)d_out;

    dim3 block(64, 4, 1);
    dim3 grid(2 * N * (N / 4), 1, 1);   // 32768 blocks, swizzled in-kernel

    calc_divergence_4406636445920_kernel<<<grid, block, 0, stream>>>(xin, out);
}